// Round 7
// baseline (448.529 us; speedup 1.0000x reference)
//
#include <hip/hip_runtime.h>
#include <cstdint>

// ---------------------------------------------------------------------------
// dysOpt: Davis-Yin splitting, 262144 rows x 64 vars, dynamic T.
//
// x20 u-space iteration (U = 20*(z + C-offset), CC = 20*C):
//   m'  = med3(U, CC, CC+20)              (= 20*(clamp(z,0,1)+C))
//   U+  = K1*m' - c[j]                    <- raw c, no 0.05 precompute; the
//                                            per-elem update is independent of
//                                            the row reduction (u-space trick)
//   Sx  = 0.05*(Sm' - 64*CC) ; t = K2*Sx - R ; corr20 = t*(20/64) - 10
//   R+  = R - Sx + 32 ; CC+ = K1*CC + corr20
// Exact algebra vs reference; scalar rescale rounding ~1 ulp/iter, damped by
// the K1=0.9975 contraction (steady-state ~1e-4 << 0.02 threshold; absmax has
// sat at the bf16 floor 0.0039 for 5 rounds).
//
// Layout: 32 elems/lane, 2 lanes/row, 32 rows/wave, 8192 waves.
// __launch_bounds__(256,4): 128-VGPR budget so U[32]+c[32] stay resident
// (round-6 post-mortem: VGPR_Count=32 proved the compiler rematerialized ac
// every iter = the 100-vs-57 instr gap), and 8192 waves / (1024 SIMD x 4) =
// exactly 2 occupancy rounds (uniform work -> quantization matters).
//
// Structure: probe (8192 rows, checked every iter) -> Ts = max Tr <= T;
// pass1: P = Ts-2 unchecked iters then checked to wave all-pass = ib
// (argmax wave reports exactly T: residual monotone per row, checked phase
// starts at P+1 <= Ts <= T); checkpoint z(ib), atomicMax T.
// pass2: resume ib -> T, +1 differentiable step, clamp, store.
// Convergence check: ds400 = q2 - 2*dCC*q1 + 64*dCC^2 <= 400*TOL^2 = 0.04,
// q1 = sum(dU), q2 = sum(dU^2) per row.
// ---------------------------------------------------------------------------

#ifndef JAX_PARTITIONABLE
#define JAX_PARTITIONABLE 1
#endif

#define BATCHN 262144
#define MAXIT  200
#define RPW    32                         // rows per wave (2 lanes/row)
#define NWAVES (BATCHN / RPW)             // 8192
#define PROBE_ROWS 8192
#define PROBE_WAVES (PROBE_ROWS / RPW)    // 256

#define K1 0.9975f   // 1 - a^2
#define K2 1.9975f   // 2 - a^2

__device__ __forceinline__ void tf2x32(uint32_t x0, uint32_t x1,
                                       uint32_t& o0, uint32_t& o1) {
  const uint32_t k0 = 0u, k1 = 1u;                 // jax.random.key(1) -> [0,1]
  const uint32_t k2 = 0x1BD11BDAu ^ k0 ^ k1;
  x0 += k0; x1 += k1;
#define TFR(r) { x0 += x1; x1 = (x1 << (r)) | (x1 >> (32 - (r))); x1 ^= x0; }
  TFR(13) TFR(15) TFR(26) TFR(6)   x0 += k1; x1 += k2 + 1u;
  TFR(17) TFR(29) TFR(16) TFR(24)  x0 += k2; x1 += k0 + 2u;
  TFR(13) TFR(15) TFR(26) TFR(6)   x0 += k0; x1 += k1 + 3u;
  TFR(17) TFR(29) TFR(16) TFR(24)  x0 += k1; x1 += k2 + 4u;
  TFR(13) TFR(15) TFR(26) TFR(6)   x0 += k2; x1 += k0 + 5u;
#undef TFR
  o0 = x0; o1 = x1;
}

__device__ __forceinline__ float z0_at(uint32_t f) {
  uint32_t b;
#if JAX_PARTITIONABLE
  uint32_t o0, o1;
  tf2x32(0u, f, o0, o1);
  b = o0 ^ o1;
#else
  const uint32_t H = 8388608u;
  uint32_t lo = (f < H) ? f : (f - H);
  uint32_t o0, o1;
  tf2x32(lo, lo + H, o0, o1);
  b = (f < H) ? o0 : o1;
#endif
  return __uint_as_float((b >> 9) | 0x3f800000u) - 1.0f;
}

// ---- fast iteration: 3 VALU/elem, no convergence check --------------------
__device__ __forceinline__ void fast_iter(float U[32], const float c[32],
                                          float& CC, float& R) {
  const float Ch = CC + 20.0f;
  float g[8];
#pragma unroll
  for (int q = 0; q < 8; ++q) {
    float m0 = __builtin_amdgcn_fmed3f(U[4 * q + 0], CC, Ch);
    float m1 = __builtin_amdgcn_fmed3f(U[4 * q + 1], CC, Ch);
    float m2 = __builtin_amdgcn_fmed3f(U[4 * q + 2], CC, Ch);
    float m3 = __builtin_amdgcn_fmed3f(U[4 * q + 3], CC, Ch);
    U[4 * q + 0] = __builtin_fmaf(K1, m0, -c[4 * q + 0]);
    U[4 * q + 1] = __builtin_fmaf(K1, m1, -c[4 * q + 1]);
    U[4 * q + 2] = __builtin_fmaf(K1, m2, -c[4 * q + 2]);
    U[4 * q + 3] = __builtin_fmaf(K1, m3, -c[4 * q + 3]);
    g[q] = (m0 + m1) + (m2 + m3);
  }
  float s = ((g[0] + g[1]) + (g[2] + g[3])) + ((g[4] + g[5]) + (g[6] + g[7]));
  s += __shfl_xor(s, 1);                              // Sm' over the row
  float Sx = 0.05f * __builtin_fmaf(-64.0f, CC, s);   // (Sm' - 64CC)/20
  float t  = __builtin_fmaf(K2, Sx, -R);
  float corr20 = __builtin_fmaf(t, 0.3125f, -10.0f);  // 20*(t/64 - 0.5)
  R = (R - Sx) + 32.0f;
  CC = __builtin_fmaf(K1, CC, corr20);
}

// ---- checked iteration: returns 400*||dz_row||^2 (replicated in the pair) -
__device__ __forceinline__ float chk_iter(float U[32], const float c[32],
                                          float& CC, float& R) {
  const float Ch = CC + 20.0f;
  float g[8];
  float q1 = 0.0f, q2 = 0.0f;
#pragma unroll
  for (int q = 0; q < 8; ++q) {
    float m0 = __builtin_amdgcn_fmed3f(U[4 * q + 0], CC, Ch);
    float m1 = __builtin_amdgcn_fmed3f(U[4 * q + 1], CC, Ch);
    float m2 = __builtin_amdgcn_fmed3f(U[4 * q + 2], CC, Ch);
    float m3 = __builtin_amdgcn_fmed3f(U[4 * q + 3], CC, Ch);
    g[q] = (m0 + m1) + (m2 + m3);
#pragma unroll
    for (int e = 0; e < 4; ++e) {
      int j = 4 * q + e;
      float m = (e == 0) ? m0 : (e == 1) ? m1 : (e == 2) ? m2 : m3;
      float un = __builtin_fmaf(K1, m, -c[j]);
      float d = un - U[j];
      q1 += d;
      q2 = __builtin_fmaf(d, d, q2);
      U[j] = un;
    }
  }
  float s = ((g[0] + g[1]) + (g[2] + g[3])) + ((g[4] + g[5]) + (g[6] + g[7]));
  s += __shfl_xor(s, 1);
  float Sx = 0.05f * __builtin_fmaf(-64.0f, CC, s);
  float t  = __builtin_fmaf(K2, Sx, -R);
  float corr20 = __builtin_fmaf(t, 0.3125f, -10.0f);
  R = (R - Sx) + 32.0f;
  float CCn = __builtin_fmaf(K1, CC, corr20);
  float dCC = CCn - CC;
  CC = CCn;
  q1 += __shfl_xor(q1, 1);
  q2 += __shfl_xor(q2, 1);
  // 400*ds = q2 - 2*dCC*q1 + 64*dCC^2
  float a = __builtin_fmaf(64.0f, dCC, -2.0f * q1);
  return __builtin_fmaf(dCC, a, q2);
}

__device__ __forceinline__ void load_c(const float* __restrict__ cost,
                                       int base, float c[32]) {
#pragma unroll
  for (int k = 0; k < 8; ++k) {
    const float4 cq = *(const float4*)(cost + base + 4 * k);
    c[4 * k + 0] = cq.x; c[4 * k + 1] = cq.y;
    c[4 * k + 2] = cq.z; c[4 * k + 3] = cq.w;
  }
}

__device__ __forceinline__ void init_state(const float* __restrict__ cost,
                                           int base, float c[32], float U[32],
                                           float& CC, float& R) {
  load_c(cost, base, c);
  float r = 0.0f;
#pragma unroll
  for (int j = 0; j < 32; ++j) {
    float z0 = z0_at((uint32_t)(base + j));
    U[j] = 20.0f * z0;
    r = __builtin_fmaf(0.05f, c[j], r + z0);   // r += z0 + 0.05*c
  }
  r += __shfl_xor(r, 1);
  R = r;                                        // R = Sz + a*Sc
  CC = 0.0f;
}

// --- probe: rows [0, PROBE_ROWS), checked every iter, atomicMax Ts ---------
__global__ __launch_bounds__(256, 4) void dys_probe(
    const float* __restrict__ cost, int* __restrict__ Tsample) {
  const int lane = threadIdx.x & 63;
  const int gw = blockIdx.x * 4 + (threadIdx.x >> 6);
  const int base = (gw * RPW + (lane >> 1)) * 64 + (lane & 1) * 32;

  float c[32], U[32], CC, R;
  init_state(cost, base, c, U, CC, R);

  int ib = MAXIT;
  for (int i = 1; i <= MAXIT; ++i) {
    float ds = chk_iter(U, c, CC, R);
    if (__all(ds <= 0.04f)) { ib = i; break; }   // wave-max Tr
  }
  if (lane == 0) atomicMax(Tsample, ib);
}

// --- pass1: P unchecked iters, checked to wave all-pass; checkpoint --------
__global__ __launch_bounds__(256, 4) void dys_pass1(
    const float* __restrict__ cost, const int* __restrict__ Tsample,
    int* __restrict__ Tglob, int* __restrict__ TrArr,
    float* __restrict__ zst) {
  const int lane = threadIdx.x & 63;
  const int gw = blockIdx.x * 4 + (threadIdx.x >> 6);
  const int base = (gw * RPW + (lane >> 1)) * 64 + (lane & 1) * 32;

  float c[32], U[32], CC, R;
  init_state(cost, base, c, U, CC, R);

  const int Ts = *Tsample;                 // uniform
  const int P = (Ts > 2) ? (Ts - 2) : 0;   // checked phase starts <= Ts <= T

  for (int i = 0; i < P; ++i) fast_iter(U, c, CC, R);

  int ib = MAXIT;
  for (int i = P + 1; i <= MAXIT; ++i) {
    float ds = chk_iter(U, c, CC, R);
    if (__all(ds <= 0.04f)) { ib = i; break; }
  }
  // ib = max(P+1, wave-max Tr) <= T; the argmax wave reports exactly T.

  const float CC05 = 0.05f * CC;           // z = 0.05*U - 0.05*CC
#pragma unroll
  for (int k = 0; k < 8; ++k) {
    float4 zq;
    zq.x = __builtin_fmaf(0.05f, U[4 * k + 0], -CC05);
    zq.y = __builtin_fmaf(0.05f, U[4 * k + 1], -CC05);
    zq.z = __builtin_fmaf(0.05f, U[4 * k + 2], -CC05);
    zq.w = __builtin_fmaf(0.05f, U[4 * k + 3], -CC05);
    *(float4*)(zst + base + 4 * k) = zq;
  }
  if (lane == 0) {
    TrArr[gw] = ib;
    atomicMax(Tglob, ib);
  }
}

// --- pass2: resume ib -> T, +1 differentiable step, clamp, store -----------
__global__ __launch_bounds__(256, 4) void dys_pass2(
    const float* __restrict__ cost, const int* __restrict__ Tglob,
    const int* __restrict__ TrArr, const float* __restrict__ zst,
    float* __restrict__ out) {
  const int lane = threadIdx.x & 63;
  const int gw = blockIdx.x * 4 + (threadIdx.x >> 6);
  const int base = (gw * RPW + (lane >> 1)) * 64 + (lane & 1) * 32;

  float c[32], U[32];
  load_c(cost, base, c);
  float r = 0.0f;
#pragma unroll
  for (int k = 0; k < 8; ++k) {
    const float4 zq = *(const float4*)(zst + base + 4 * k);
    U[4 * k + 0] = 20.0f * zq.x; U[4 * k + 1] = 20.0f * zq.y;
    U[4 * k + 2] = 20.0f * zq.z; U[4 * k + 3] = 20.0f * zq.w;
    r += (zq.x + zq.y) + (zq.z + zq.w);
  }
#pragma unroll
  for (int j = 0; j < 32; ++j) r = __builtin_fmaf(0.05f, c[j], r);
  float CC = 0.0f;
  float R = r + __shfl_xor(r, 1);          // R = Sz + a*Sc (invariant)

  const int T = *Tglob;
  const int ib = TrArr[gw];                // wave-uniform

  // (T - ib) lockstep iters to z(T), +1 differentiable step
  for (int i = ib; i <= T; ++i) fast_iter(U, c, CC, R);

  const float CC05 = 0.05f * CC;
#pragma unroll
  for (int k = 0; k < 8; ++k) {
    float4 o;
    o.x = __builtin_amdgcn_fmed3f(
        __builtin_fmaf(0.05f, U[4 * k + 0], -CC05), 0.0f, 1.0f);
    o.y = __builtin_amdgcn_fmed3f(
        __builtin_fmaf(0.05f, U[4 * k + 1], -CC05), 0.0f, 1.0f);
    o.z = __builtin_amdgcn_fmed3f(
        __builtin_fmaf(0.05f, U[4 * k + 2], -CC05), 0.0f, 1.0f);
    o.w = __builtin_amdgcn_fmed3f(
        __builtin_fmaf(0.05f, U[4 * k + 3], -CC05), 0.0f, 1.0f);
    *(float4*)(out + base + 4 * k) = o;
  }
}

extern "C" void kernel_launch(void* const* d_in, const int* in_sizes, int n_in,
                              void* d_out, int out_size, void* d_ws,
                              size_t ws_size, hipStream_t stream) {
  const float* cost = (const float*)d_in[0];
  float* out = (float*)d_out;

  // ws: [0..4) Tglob ; [4..8) Tsample ; [1024..) TrArr[8192] ; then z ckpt
  int* Tglob   = (int*)d_ws;
  int* Tsample = (int*)d_ws + 1;
  const size_t TR_OFF = 1024;
  const size_t Z_OFF  = TR_OFF + (size_t)NWAVES * sizeof(int);  // 16B-aligned
  int*   TrArr = (int*)((char*)d_ws + TR_OFF);
  float* zst   = (float*)((char*)d_ws + Z_OFF);

  hipMemsetAsync(d_ws, 0, 8, stream);   // Tglob = Tsample = 0

  dim3 block(256);
  dys_probe<<<dim3(PROBE_WAVES / 4), block, 0, stream>>>(cost, Tsample);
  dys_pass1<<<dim3(NWAVES / 4), block, 0, stream>>>(cost, Tsample, Tglob,
                                                    TrArr, zst);
  dys_pass2<<<dim3(NWAVES / 4), block, 0, stream>>>(cost, Tglob, TrArr, zst,
                                                    out);
}